// Round 13
// baseline (146.684 us; speedup 1.0000x reference)
//
#include <hip/hip_runtime.h>
#include <math.h>

#define L 4096

// edge tables
__constant__ int c_EV[12]   = {1,0,2,3,4,5,1,1,1,5,1,4};      // dest v of edge e
__constant__ int c_INOFF[7] = {0,1,6,7,8,10,12};              // incoming-edge offsets per v
__constant__ int c_INE[12]  = {1, 0,6,7,8,10, 2, 3, 4,11, 5,9}; // incoming edge ids

__device__ inline float sigmf(float x){ return 1.f/(1.f+expf(-x)); }

// ---------------- K1: softmax over L of p_att rows (blocks 0..23) + weight repack (block 24) ----------------
__global__ __launch_bounds__(256) void k_softmax_norm(const float* __restrict__ p_atts,
                                                      float* __restrict__ norm,
                                                      const float* __restrict__ W_rel1,
                                                      const float* __restrict__ W_att,
                                                      const float* __restrict__ W_proj,
                                                      float* __restrict__ wt2,
                                                      float* __restrict__ wpack){
  int tid = threadIdx.x;
  if (blockIdx.x == 24){
    // wt2[ci][h][k][co10]: 90-dword SGPR slices
    for (int i = tid; i < 3600; i += 256){
      int co = i % 10; int t = i / 10;
      int k = t % 9; t /= 9;
      int h = t & 1; int ci = t >> 1;
      wt2[i] = W_rel1[(((h * 10 + co) * 20) + ci) * 9 + k];
    }
    // wpack[c][24]: f<12 -> W_att col, f<22 -> W_proj col, else 0
    for (int i = tid; i < 256 * 24; i += 256){
      int c = i / 24, f = i % 24;
      float v = 0.f;
      if (f < 12)      v = W_att[f * 257 + 1 + c];
      else if (f < 22) v = W_proj[(f - 12) * 256 + c];
      wpack[i] = v;
    }
    return;
  }
  int pn = blockIdx.x;                       // p*4+n
  const float* src = p_atts + (size_t)(pn + 4) * L;   // (p+1)*4+n
  float* dst = norm + (size_t)pn * L;
  __shared__ float red[256];
  float m = -1e30f;
  for (int l = tid; l < L; l += 256) m = fmaxf(m, src[l]);
  red[tid] = m; __syncthreads();
  for (int s = 128; s; s >>= 1){ if (tid < s) red[tid] = fmaxf(red[tid], red[tid+s]); __syncthreads(); }
  m = red[0]; __syncthreads();
  float sum = 0.f;
  for (int l = tid; l < L; l += 256) sum += expf(src[l] - m);
  red[tid] = sum; __syncthreads();
  for (int s = 128; s; s >>= 1){ if (tid < s) red[tid] += red[tid+s]; __syncthreads(); }
  float inv = 1.f / red[0];
  for (int l = tid; l < L; l += 256) dst[l] = expf(src[l] - m) * inv;
}

__device__ inline float coord_feat(int cc, int l){
  int h = l >> 6, w = l & 63;
  const float s = 2.f / 64.f;
  switch (cc){
    case 0: return w * s - 1.f;
    case 1: return h * s - 1.f;
    case 2: return (w + 1) * s - 1.f;
    case 3: return (h + 1) * s - 1.f;
    case 4: return (w + 0.5f) * s - 1.f;
    case 5: return (h + 0.5f) * s - 1.f;
    default: return 1.f / 64.f;
  }
}

// ---------------- K2: centroids — 2 channels/block, norm loaded once per pixel ----------------
__global__ __launch_bounds__(256) void k_centroid(const float* __restrict__ xp,
                                                  const float* __restrict__ norm,
                                                  float* __restrict__ cen){
  int c0 = blockIdx.x;         // 0..131 -> channels c0 and c0+132
  int c1 = c0 + 132;
  int n = blockIdx.y;          // 0..3
  int tid = threadIdx.x;
  float acc[2][6];
#pragma unroll
  for (int q = 0; q < 2; q++)
#pragma unroll
    for (int p = 0; p < 6; p++) acc[q][p] = 0.f;
  const float* nr0 = norm + (size_t)n * L;
  const float* xr0 = xp + ((size_t)n * 256 + c0) * L;
  const float* xr1 = (c1 < 256) ? xp + ((size_t)n * 256 + c1) * L : nullptr;
  int cc1 = c1 - 256;
  for (int l = tid; l < L; l += 256){
    float nv[6];
#pragma unroll
    for (int p = 0; p < 6; p++) nv[p] = nr0[(size_t)p * 4 * L + l];
    float x0 = xr0[l];
    float x1 = (c1 < 256) ? xr1[l] : coord_feat(cc1, l);
#pragma unroll
    for (int p = 0; p < 6; p++){
      acc[0][p] = fmaf(x0, nv[p], acc[0][p]);
      acc[1][p] = fmaf(x1, nv[p], acc[1][p]);
    }
  }
#pragma unroll
  for (int q = 0; q < 2; q++)
#pragma unroll
    for (int p = 0; p < 6; p++){
      for (int off = 32; off; off >>= 1) acc[q][p] += __shfl_xor(acc[q][p], off, 64);
    }
  __shared__ float red[2][6][4];
  int wv = tid >> 6;
  if ((tid & 63) == 0){
#pragma unroll
    for (int q = 0; q < 2; q++)
#pragma unroll
      for (int p = 0; p < 6; p++) red[q][p][wv] = acc[q][p];
  }
  __syncthreads();
  if (tid < 12){
    int q = tid / 6, p = tid % 6;
    float s = red[q][p][0] + red[q][p][1] + red[q][p][2] + red[q][p][3];
    cen[(size_t)(p * 4 + n) * 264 + (q ? c1 : c0)] = s;
  }
}

// ---------------- K3: q then qk = q @ W_key, qb = q . b_key ----------------
__global__ __launch_bounds__(256) void k_qk(const float* __restrict__ cen,
                                            const float* __restrict__ W_q, const float* __restrict__ b_q,
                                            const float* __restrict__ W_key, const float* __restrict__ b_key,
                                            float* __restrict__ qk, float* __restrict__ qb){
  int pn = blockIdx.x;
  int tid = threadIdx.x;
  __shared__ float cen_s[264];
  __shared__ float qs[64];
  __shared__ float part[256];
  for (int i = tid; i < 264; i += 256) cen_s[i] = cen[(size_t)pn * 264 + i];
  __syncthreads();
  int o = tid >> 2, pr = tid & 3;
  {
    float a = 0.f;
    int f0 = pr * 66;
    for (int j = 0; j < 66; j++){ int f = f0 + j; a = fmaf(cen_s[f], W_q[o * 264 + f], a); }
    part[tid] = a;
  }
  __syncthreads();
  if (pr == 0) qs[o] = part[tid] + part[tid + 1] + part[tid + 2] + part[tid + 3] + b_q[o];
  __syncthreads();
  for (int c = tid; c < 264; c += 256){
    float a = 0.f;
    for (int oo = 0; oo < 64; oo++) a = fmaf(qs[oo], W_key[oo * 264 + c], a);
    qk[(size_t)pn * 264 + c] = a;
  }
  if (tid < 64) part[tid] = qs[tid] * b_key[tid];
  __syncthreads();
  if (tid == 0){
    float a = 0.f;
    for (int oo = 0; oo < 64; oo++) a += part[oo];
    qb[pn] = a;
  }
}

// ---------------- K4: fused per-pixel kernel; SGPR weights via wpack; msg-BN-stat partials ----------------
__global__ __launch_bounds__(256) void k_pixel(const float* __restrict__ xp,
                                              const float* __restrict__ p_atts,
                                              const float* __restrict__ W_att, const float* __restrict__ b_att,
                                              const float* __restrict__ wpack,
                                              const float* __restrict__ qk, const float* __restrict__ qb,
                                              float* __restrict__ out_fdep,
                                              float* __restrict__ s_edge,
                                              float* __restrict__ proj_x,
                                              float* __restrict__ mpart){
  __shared__ float s_qk[256 * 8];      // [c][p] (pad 6->8 with zeros)
  __shared__ float s_qkt[48];          // [p][cc] coord tail
  __shared__ float pacc[4][28][64];
  __shared__ float w0[12], ba[12], qbs[6];
  int n = blockIdx.y;
  int tid = threadIdx.x;
  int wv = tid >> 6, w = tid & 63;
  int l = blockIdx.x * 64 + w;
  for (int i = tid; i < 256 * 8; i += 256){ int c = i >> 3, p = i & 7; s_qk[i] = (p < 6) ? qk[((size_t)(p * 4 + n)) * 264 + c] : 0.f; }
  if (tid < 48){ int p = tid >> 3, cc = tid & 7; s_qkt[tid] = qk[((size_t)(p * 4 + n)) * 264 + 256 + cc]; }
  if (tid < 12){ w0[tid] = W_att[tid * 257]; ba[tid] = b_att[tid]; }
  if (tid < 6) qbs[tid] = qb[tid * 4 + n];
  __syncthreads();

  float a[28];
#pragma unroll
  for (int f = 0; f < 28; f++) a[f] = 0.f;
  const float* xpn = xp + (size_t)n * 256 * L + l;
  int c0 = wv * 64;
  for (int cc = 0; cc < 64; cc += 4){
    float xv4[4];
#pragma unroll
    for (int u = 0; u < 4; u++) xv4[u] = xpn[(size_t)(c0 + cc + u) * L];
#pragma unroll
    for (int u = 0; u < 4; u++){
      int c = c0 + cc + u;
      float xv = xv4[u];
      const float* wp = wpack + c * 24;          // wave-uniform -> s_load
#pragma unroll
      for (int f = 0; f < 22; f++) a[f] = fmaf(xv, wp[f], a[f]);
      float4 q0 = *(const float4*)(s_qk + c * 8);
      float4 q1 = *(const float4*)(s_qk + c * 8 + 4);
      a[22] = fmaf(xv, q0.x, a[22]); a[23] = fmaf(xv, q0.y, a[23]);
      a[24] = fmaf(xv, q0.z, a[24]); a[25] = fmaf(xv, q0.w, a[25]);
      a[26] = fmaf(xv, q1.x, a[26]); a[27] = fmaf(xv, q1.y, a[27]);
    }
  }
#pragma unroll
  for (int f = 0; f < 28; f++) pacc[wv][f][w] = a[f];
  __syncthreads();
  for (int idx = tid; idx < 28 * 64; idx += 256){
    int f = idx >> 6, ww = idx & 63;
    pacc[0][f][ww] = pacc[0][f][ww] + pacc[1][f][ww] + pacc[2][f][ww] + pacc[3][f][ww];
  }
  __syncthreads();
  float* se_lds = &pacc[1][0][0];       // 12*64 floats, free after reduce
  if (tid < 64){
    float accA[12], accP[10], accE[6];
#pragma unroll
    for (int j = 0; j < 12; j++) accA[j] = pacc[0][j][w];
#pragma unroll
    for (int k = 0; k < 10; k++) accP[k] = pacc[0][12 + k][w];
#pragma unroll
    for (int p = 0; p < 6; p++) accE[p] = pacc[0][22 + p][w];

    float cf[8];
    { int hh = l >> 6, ww2 = l & 63; const float s = 2.f / 64.f;
      cf[0] = ww2 * s - 1.f; cf[1] = hh * s - 1.f; cf[2] = (ww2 + 1) * s - 1.f; cf[3] = (hh + 1) * s - 1.f;
      cf[4] = (ww2 + 0.5f) * s - 1.f; cf[5] = (hh + 0.5f) * s - 1.f; cf[6] = 1.f / 64.f; cf[7] = 1.f / 64.f; }
    float sat[6];
#pragma unroll
    for (int p = 0; p < 6; p++){
      float e = accE[p] + qbs[p];
#pragma unroll
      for (int cc = 0; cc < 8; cc++) e = fmaf(cf[cc], s_qkt[p * 8 + cc], e);
      float aa = sigmf(e);
      float pa = p_atts[((size_t)(p + 1) * 4 + n) * L + l];
      sat[p] = aa * (1.f - pa);
    }
    const int part_of[12] = {0,1,1,1,1,1,2,3,4,4,5,5};
    float lg[12];
#pragma unroll
    for (int j = 0; j < 12; j++){
      lg[j] = accA[j] + w0[j] * sat[part_of[j]] + ba[j];
      out_fdep[((size_t)n * 12 + j) * L + l] = lg[j];
    }
    const int gs[6] = {0,1,6,7,8,10}, gd[6] = {1,5,1,1,2,2};
    float sm[12];
#pragma unroll
    for (int g = 0; g < 6; g++){
      int s0 = gs[g], d = gd[g];
      float mx = lg[s0];
      for (int t = 1; t < d; t++) mx = fmaxf(mx, lg[s0 + t]);
      float ssum = 0.f;
      for (int t = 0; t < d; t++){ float e2 = expf(lg[s0 + t] - mx); sm[s0 + t] = e2; ssum += e2; }
      float inv = 1.f / ssum;
      for (int t = 0; t < d; t++) sm[s0 + t] *= inv;
    }
#pragma unroll
    for (int e = 0; e < 12; e++){
      float sev = sat[part_of[e]] * sm[e];
      s_edge[((size_t)e * 4 + n) * L + l] = sev;
      se_lds[e * 64 + w] = sev;
    }
#pragma unroll
    for (int k = 0; k < 10; k++) proj_x[((size_t)n * 10 + k) * L + l] = accP[k];
  }
  __syncthreads();
  // msg BN-stat partials: pair = e*10+k, t = se[e]*projx[k]; block-sum over 64 pixels
  {
    int blk = n * 64 + blockIdx.x;       // 0..255
#pragma unroll
    for (int j = 0; j < 30; j++){
      int pair = wv * 30 + j;
      int e = pair / 10, k = pair % 10;
      float t = se_lds[e * 64 + w] * pacc[0][12 + k][w];
      float s1 = t, s2 = t * t;
      for (int off = 32; off; off >>= 1){ s1 += __shfl_xor(s1, off, 64); s2 += __shfl_xor(s2, off, 64); }
      if (w == 0){
        mpart[((size_t)pair * 256 + blk) * 2]     = s1;
        mpart[((size_t)pair * 256 + blk) * 2 + 1] = s2;
      }
    }
  }
}

// ---------------- K7: conv3x3, 2 output rows/thread; inline mpart reduce for BN params ----------------
// block = 256 thr = 4 waves, wave = 2 rows; grid (8 rowblocks, 4 n, 24 (e,h))
__global__ __launch_bounds__(256) void k_conv3(const float* __restrict__ proj_x,
                                               const float* __restrict__ s_edge,
                                               const float* __restrict__ mpart,
                                               const float* __restrict__ g_proj, const float* __restrict__ bt_proj,
                                               const float* __restrict__ p_nodes,
                                               const float* __restrict__ wt2,
                                               float* __restrict__ y,
                                               float* __restrict__ ypart){
  __shared__ float red[4][20];
  __shared__ float scs_s[10], sbs_s[10];
  int rb = blockIdx.x, n = blockIdx.y;
  int e = blockIdx.z >> 1, h = blockIdx.z & 1;
  int v = c_EV[e];
  int tid = threadIdx.x;
  int wv = tid >> 6, w = tid & 63;
  int r0 = rb * 8 + wv * 2;               // output rows r0, r0+1; inputs r0-1 .. r0+2
  float mLm = (w == 0) ? 0.f : 1.f;
  float mRm = (w == 63) ? 0.f : 1.f;

  // inline reduce of msg BN stats (10 entries for this e), waves round-robin
  for (int k = wv; k < 10; k += 4){
    const float* mp = mpart + (size_t)(e * 10 + k) * 512;
    float s1 = mp[w * 2] + mp[(w + 64) * 2] + mp[(w + 128) * 2] + mp[(w + 192) * 2];
    float s2 = mp[w * 2 + 1] + mp[(w + 64) * 2 + 1] + mp[(w + 128) * 2 + 1] + mp[(w + 192) * 2 + 1];
    for (int off = 32; off; off >>= 1){ s1 += __shfl_xor(s1, off, 64); s2 += __shfl_xor(s2, off, 64); }
    if (w == 0){
      float m = s1 / 16384.f, vv = s2 / 16384.f - m * m;
      float istd = rsqrtf(vv + 1e-5f);
      float s = istd * g_proj[k];
      scs_s[k] = s; sbs_s[k] = bt_proj[k] - m * s;
    }
  }
  __syncthreads();
  float scs[10], sbs[10];
#pragma unroll
  for (int k = 0; k < 10; k++){ scs[k] = scs_s[k]; sbs[k] = sbs_s[k]; }

  const size_t enL = ((size_t)e * 4 + n) * L;
  const float* se = s_edge + enL;
  float se4[4];
#pragma unroll
  for (int j = 0; j < 4; j++){
    int rr = r0 - 1 + j;
    se4[j] = (rr >= 0 && rr < 64) ? se[rr * 64 + w] : 0.f;
  }

  float acc0[10], acc1[10];
#pragma unroll
  for (int co = 0; co < 10; co++){ acc0[co] = 0.f; acc1[co] = 0.f; }

  for (int ci = 0; ci < 10; ci++){
    const float* pr = proj_x + ((size_t)n * 10 + ci) * L;
    float mC[4];
#pragma unroll
    for (int j = 0; j < 4; j++){
      int rr = r0 - 1 + j;
      if (rr >= 0 && rr < 64){
        float t = pr[rr * 64 + w] * se4[j];
        mC[j] = fmaxf(fmaf(t, scs[ci], sbs[ci]), 0.f);
      } else mC[j] = 0.f;
    }
    float mL[4], mR[4];
#pragma unroll
    for (int j = 0; j < 4; j++){
      mL[j] = __shfl_up(mC[j], 1) * mLm;
      mR[j] = __shfl_down(mC[j], 1) * mRm;
    }
    const float* wp = wt2 + (ci * 2 + h) * 90;   // wave-uniform -> SGPRs
#pragma unroll
    for (int ky = 0; ky < 3; ky++){
#pragma unroll
      for (int co = 0; co < 10; co++){
        float w0v = wp[(ky * 3 + 0) * 10 + co];
        float w1v = wp[(ky * 3 + 1) * 10 + co];
        float w2v = wp[(ky * 3 + 2) * 10 + co];
        acc0[co] = fmaf(mL[ky], w0v, fmaf(mC[ky], w1v, fmaf(mR[ky], w2v, acc0[co])));
        acc1[co] = fmaf(mL[ky + 1], w0v, fmaf(mC[ky + 1], w1v, fmaf(mR[ky + 1], w2v, acc1[co])));
      }
    }
  }
  for (int ci = 10; ci < 20; ci++){
    const float* pnp = p_nodes + (((size_t)v * 4 + n) * 10 + (ci - 10)) * L;
    float mC[4];
#pragma unroll
    for (int j = 0; j < 4; j++){
      int rr = r0 - 1 + j;
      mC[j] = (rr >= 0 && rr < 64) ? pnp[rr * 64 + w] : 0.f;
    }
    float mL[4], mR[4];
#pragma unroll
    for (int j = 0; j < 4; j++){
      mL[j] = __shfl_up(mC[j], 1) * mLm;
      mR[j] = __shfl_down(mC[j], 1) * mRm;
    }
    const float* wp = wt2 + (ci * 2 + h) * 90;
#pragma unroll
    for (int ky = 0; ky < 3; ky++){
#pragma unroll
      for (int co = 0; co < 10; co++){
        float w0v = wp[(ky * 3 + 0) * 10 + co];
        float w1v = wp[(ky * 3 + 1) * 10 + co];
        float w2v = wp[(ky * 3 + 2) * 10 + co];
        acc0[co] = fmaf(mL[ky], w0v, fmaf(mC[ky], w1v, fmaf(mR[ky], w2v, acc0[co])));
        acc1[co] = fmaf(mL[ky + 1], w0v, fmaf(mC[ky + 1], w1v, fmaf(mR[ky + 1], w2v, acc1[co])));
      }
    }
  }

  int ch0 = h * 10;
#pragma unroll
  for (int co = 0; co < 10; co++){
    size_t base = enL * 20 + ((size_t)(ch0 + co)) * L;
    y[base + r0 * 64 + w] = acc0[co];
    y[base + (r0 + 1) * 64 + w] = acc1[co];
  }

  // per-block BN partials for y
#pragma unroll
  for (int co = 0; co < 10; co++){
    float s1 = acc0[co] + acc1[co];
    float s2 = acc0[co] * acc0[co] + acc1[co] * acc1[co];
    for (int off = 32; off; off >>= 1){ s1 += __shfl_xor(s1, off, 64); s2 += __shfl_xor(s2, off, 64); }
    if (w == 0){ red[wv][2 * co] = s1; red[wv][2 * co + 1] = s2; }
  }
  __syncthreads();
  if (tid < 20){
    int co = tid >> 1, which = tid & 1;
    float s = red[0][tid] + red[1][tid] + red[2][tid] + red[3][tid];
    ypart[(((size_t)(e * 20 + ch0 + co) * 32) + n * 8 + rb) * 2 + which] = s;
  }
}

// ---------------- K9: fused mout + gather + GRU; inline ypart reduce; cnm-stat partials ----------------
__global__ __launch_bounds__(256) void k_mout_gru(const float* __restrict__ y,
                                                  const float* __restrict__ ypart,
                                                  const float* __restrict__ g_rel1, const float* __restrict__ bt_rel1,
                                                  const float* __restrict__ W_rel2, const float* __restrict__ b_rel2,
                                                  const float* __restrict__ p_nodes,
                                                  const float* __restrict__ Wg, const float* __restrict__ bg,
                                                  const float* __restrict__ Wc,
                                                  float* __restrict__ cnm, float* __restrict__ zbuf,
                                                  float* __restrict__ cpart){
  int i = blockIdx.z, n = blockIdx.y;
  int tid = threadIdx.x;
  int l = blockIdx.x * 256 + tid;
  __shared__ float w2[200], wc[200], wg[40], bgs[2];
  __shared__ float sc[5][20], sb[5][20];
  __shared__ float red[4][20];
  int ne = c_INOFF[i + 1] - c_INOFF[i];
  for (int t = tid; t < 200; t += 256){ w2[t] = W_rel2[t]; wc[t] = Wc[i * 200 + t]; }
  if (tid < 40) wg[tid] = Wg[i * 40 + tid];
  if (tid < 2) bgs[tid] = bg[i * 2 + tid];
  if (tid < ne * 20){
    int ei = tid / 20, c = tid % 20;
    int e = c_INE[c_INOFF[i] + ei];
    int ec = e * 20 + c;
    float s1 = 0.f, s2 = 0.f;
#pragma unroll 8
    for (int t = 0; t < 32; t++){
      s1 += ypart[((size_t)ec * 32 + t) * 2];
      s2 += ypart[((size_t)ec * 32 + t) * 2 + 1];
    }
    float m = s1 / 16384.f, vv = s2 / 16384.f - m * m;
    float istd = rsqrtf(vv + 1e-5f);
    float s = istd * g_rel1[c];
    sc[ei][c] = s; sb[ei][c] = bt_rel1[c] - m * s;
  }
  __syncthreads();
  float m[10];
#pragma unroll
  for (int k = 0; k < 10; k++) m[k] = 0.f;
  for (int ei = 0; ei < ne; ei++){
    int e = c_INE[c_INOFF[i] + ei];
    float z[20];
#pragma unroll
    for (int c = 0; c < 20; c++){
      float t = y[(((size_t)e * 4 + n) * 20 + c) * L + l];
      z[c] = fmaxf(t * sc[ei][c] + sb[ei][c], 0.f);
    }
#pragma unroll
    for (int k = 0; k < 10; k++){
      float a = b_rel2[k];
#pragma unroll
      for (int c = 0; c < 20; c++) a = fmaf(w2[k * 20 + c], z[c], a);
      m[k] += sigmf(a);
    }
  }
  float h[10];
#pragma unroll
  for (int k = 0; k < 10; k++) h[k] = p_nodes[(((size_t)(i + 1) * 4 + n) * 10 + k) * L + l];
  float g0 = bgs[0], g1 = bgs[1];
#pragma unroll
  for (int k = 0; k < 10; k++){
    g0 = fmaf(wg[k], m[k], g0); g0 = fmaf(wg[10 + k], h[k], g0);
    g1 = fmaf(wg[20 + k], m[k], g1); g1 = fmaf(wg[30 + k], h[k], g1);
  }
  float r = sigmf(g0), zz = sigmf(g1);
  zbuf[((size_t)i * 4 + n) * L + l] = zz;
  float cv[10];
#pragma unroll
  for (int k = 0; k < 10; k++){
    float a = 0.f;
#pragma unroll
    for (int c = 0; c < 10; c++){
      a = fmaf(wc[k * 20 + c], m[c], a);
      a = fmaf(wc[k * 20 + 10 + c], r * h[c], a);
    }
    cv[k] = a;
    cnm[(((size_t)i * 4 + n) * 10 + k) * L + l] = a;
  }
  int wv = tid >> 6, w = tid & 63;
#pragma unroll
  for (int k = 0; k < 10; k++){
    float s1 = cv[k], s2 = cv[k] * cv[k];
    for (int off = 32; off; off >>= 1){ s1 += __shfl_xor(s1, off, 64); s2 += __shfl_xor(s2, off, 64); }
    if (w == 0){ red[wv][2 * k] = s1; red[wv][2 * k + 1] = s2; }
  }
  __syncthreads();
  if (tid < 20){
    float s = red[0][tid] + red[1][tid] + red[2][tid] + red[3][tid];
    int k = tid >> 1, which = tid & 1;
    cpart[(((size_t)(i * 10 + k) * 64) + n * 16 + blockIdx.x) * 2 + which] = s;
  }
}

// ---------------- K13: final node update + part-0 copy; inline cpart reduce ----------------
__global__ __launch_bounds__(256) void k_out(const float* __restrict__ cnm, const float* __restrict__ zbuf,
                                             const float* __restrict__ p_nodes,
                                             const float* __restrict__ cpart,
                                             const float* __restrict__ g_can, const float* __restrict__ bt_can,
                                             float* __restrict__ out){
  int tid = threadIdx.x;
  int idx = blockIdx.x * 256 + tid;
  const int NODE = 4 * 10 * L;
  if (idx < NODE){ out[idx] = p_nodes[idx]; return; }   // whole block is in copy region (NODE % 256 == 0)
  int j = idx - NODE;
  int l = j & (L - 1); int r = j >> 12;
  int k = r % 10; r /= 10; int n = r & 3; int i = r >> 2;
  int ik = i * 10 + k;                                   // uniform across block
  __shared__ float smu, sistd;
  if (tid < 64){
    float s1 = cpart[((size_t)ik * 64 + tid) * 2];
    float s2 = cpart[((size_t)ik * 64 + tid) * 2 + 1];
    for (int off = 32; off; off >>= 1){ s1 += __shfl_xor(s1, off, 64); s2 += __shfl_xor(s2, off, 64); }
    if (tid == 0){
      float m = s1 / 16384.f, v = s2 / 16384.f - m * m;
      smu = m; sistd = rsqrtf(v + 1e-5f);
    }
  }
  __syncthreads();
  float c = cnm[j];
  float cn = (c - smu) * sistd * g_can[ik] + bt_can[ik];
  cn = cn > 0.f ? cn : 0.01f * cn;
  float z = zbuf[((size_t)i * 4 + n) * L + l];
  float h = p_nodes[idx];
  out[idx] = (1.f - z) * h + z * cn;
}

extern "C" void kernel_launch(void* const* d_in, const int* in_sizes, int n_in,
                              void* d_out, int out_size, void* d_ws, size_t ws_size,
                              hipStream_t stream){
  (void)in_sizes; (void)n_in; (void)out_size; (void)ws_size;
  const float* xp      = (const float*)d_in[0];
  const float* p_nodes = (const float*)d_in[1];
  const float* p_atts  = (const float*)d_in[2];
  const float* W_key   = (const float*)d_in[3];
  const float* b_key   = (const float*)d_in[4];
  const float* W_q     = (const float*)d_in[5];
  const float* b_q     = (const float*)d_in[6];
  const float* W_att   = (const float*)d_in[7];
  const float* b_att   = (const float*)d_in[8];
  const float* W_proj  = (const float*)d_in[9];
  const float* g_proj  = (const float*)d_in[10];
  const float* bt_proj = (const float*)d_in[11];
  const float* W_rel1  = (const float*)d_in[12];
  const float* g_rel1  = (const float*)d_in[13];
  const float* bt_rel1 = (const float*)d_in[14];
  const float* W_rel2  = (const float*)d_in[15];
  const float* b_rel2  = (const float*)d_in[16];
  const float* Wg      = (const float*)d_in[17];
  const float* bg      = (const float*)d_in[18];
  const float* Wc      = (const float*)d_in[19];
  const float* g_can   = (const float*)d_in[20];
  const float* bt_can  = (const float*)d_in[21];

  float* out      = (float*)d_out;
  float* fdep_out = out + (size_t)7 * 4 * 10 * L;   // xp_new first, then fdep_att

  float* w = (float*)d_ws;
  size_t off = 0;
  auto alloc = [&](size_t nf){ float* p = w + off; off += nf; return p; };
  float* norm    = alloc((size_t)6 * 4 * L);
  float* cen     = alloc(6 * 4 * 264);
  float* qk      = alloc(6 * 4 * 264);
  float* qb      = alloc(24);
  float* wt2     = alloc(3600);
  float* wpack   = alloc(256 * 24);
  float* proj_x  = alloc((size_t)4 * 10 * L);
  float* s_edge  = alloc((size_t)12 * 4 * L);
  float* mpart   = alloc(120 * 256 * 2);
  float* ybuf    = alloc((size_t)12 * 4 * 20 * L);
  float* ypart   = alloc(240 * 32 * 2);
  float* cpart   = alloc(60 * 64 * 2);
  float* cnm     = alloc((size_t)6 * 4 * 10 * L);
  float* zbuf    = alloc((size_t)6 * 4 * L);

  k_softmax_norm<<<25, 256, 0, stream>>>(p_atts, norm, W_rel1, W_att, W_proj, wt2, wpack);
  { dim3 g(132, 4); k_centroid<<<g, 256, 0, stream>>>(xp, norm, cen); }
  k_qk<<<24, 256, 0, stream>>>(cen, W_q, b_q, W_key, b_key, qk, qb);
  { dim3 g(64, 4); k_pixel<<<g, 256, 0, stream>>>(xp, p_atts, W_att, b_att, wpack, qk, qb, fdep_out, s_edge, proj_x, mpart); }
  { dim3 g(8, 4, 24); k_conv3<<<g, 256, 0, stream>>>(proj_x, s_edge, mpart, g_proj, bt_proj, p_nodes, wt2, ybuf, ypart); }
  { dim3 g(16, 4, 6); k_mout_gru<<<g, 256, 0, stream>>>(ybuf, ypart, g_rel1, bt_rel1, W_rel2, b_rel2,
                                                        p_nodes, Wg, bg, Wc, cnm, zbuf, cpart); }
  k_out<<<(7 * 4 * 10 * L) / 256, 256, 0, stream>>>(cnm, zbuf, p_nodes, cpart, g_can, bt_can, out);
}

// Round 14
// 143.223 us; speedup vs baseline: 1.0242x; 1.0242x over previous
//
#include <hip/hip_runtime.h>
#include <math.h>

#define L 4096

// edge tables
__constant__ int c_EV[12]   = {1,0,2,3,4,5,1,1,1,5,1,4};      // dest v of edge e
__constant__ int c_INOFF[7] = {0,1,6,7,8,10,12};              // incoming-edge offsets per v
__constant__ int c_INE[12]  = {1, 0,6,7,8,10, 2, 3, 4,11, 5,9}; // incoming edge ids

__device__ inline float sigmf(float x){ return 1.f/(1.f+expf(-x)); }

// ---------------- K1: softmax over L of p_att rows (blocks 0..23) + W_rel1 repack (block 24) ----------------
__global__ __launch_bounds__(256) void k_softmax_norm(const float* __restrict__ p_atts,
                                                      float* __restrict__ norm,
                                                      const float* __restrict__ W_rel1,
                                                      float* __restrict__ wt2){
  int tid = threadIdx.x;
  if (blockIdx.x == 24){
    // wt2[ci][h][k][co10]: 90-dword SGPR slices
    for (int i = tid; i < 3600; i += 256){
      int co = i % 10; int t = i / 10;
      int k = t % 9; t /= 9;
      int h = t & 1; int ci = t >> 1;
      wt2[i] = W_rel1[(((h * 10 + co) * 20) + ci) * 9 + k];
    }
    return;
  }
  int pn = blockIdx.x;                       // p*4+n
  const float* src = p_atts + (size_t)(pn + 4) * L;   // (p+1)*4+n
  float* dst = norm + (size_t)pn * L;
  __shared__ float red[256];
  float m = -1e30f;
  for (int l = tid; l < L; l += 256) m = fmaxf(m, src[l]);
  red[tid] = m; __syncthreads();
  for (int s = 128; s; s >>= 1){ if (tid < s) red[tid] = fmaxf(red[tid], red[tid+s]); __syncthreads(); }
  m = red[0]; __syncthreads();
  float sum = 0.f;
  for (int l = tid; l < L; l += 256) sum += expf(src[l] - m);
  red[tid] = sum; __syncthreads();
  for (int s = 128; s; s >>= 1){ if (tid < s) red[tid] += red[tid+s]; __syncthreads(); }
  float inv = 1.f / red[0];
  for (int l = tid; l < L; l += 256) dst[l] = expf(src[l] - m) * inv;
}

__device__ inline float coord_feat(int cc, int l){
  int h = l >> 6, w = l & 63;
  const float s = 2.f / 64.f;
  switch (cc){
    case 0: return w * s - 1.f;
    case 1: return h * s - 1.f;
    case 2: return (w + 1) * s - 1.f;
    case 3: return (h + 1) * s - 1.f;
    case 4: return (w + 0.5f) * s - 1.f;
    case 5: return (h + 0.5f) * s - 1.f;
    default: return 1.f / 64.f;
  }
}

// ---------------- K2: centroids — 4 channels/block, norm loaded once per pixel ----------------
__global__ __launch_bounds__(256) void k_centroid(const float* __restrict__ xp,
                                                  const float* __restrict__ norm,
                                                  float* __restrict__ cen){
  int c0 = blockIdx.x;         // 0..65 -> channels c0 + 66*q, q=0..3
  int n = blockIdx.y;          // 0..3
  int tid = threadIdx.x;
  int ch[4];
#pragma unroll
  for (int q = 0; q < 4; q++) ch[q] = c0 + 66 * q;
  float acc[4][6];
#pragma unroll
  for (int q = 0; q < 4; q++)
#pragma unroll
    for (int p = 0; p < 6; p++) acc[q][p] = 0.f;
  const float* nr0 = norm + (size_t)n * L;
  const float* xr[4];
#pragma unroll
  for (int q = 0; q < 4; q++)
    xr[q] = (ch[q] < 256) ? xp + ((size_t)n * 256 + ch[q]) * L : nullptr;
  for (int l = tid; l < L; l += 256){
    float nv[6];
#pragma unroll
    for (int p = 0; p < 6; p++) nv[p] = nr0[(size_t)p * 4 * L + l];
    float xv[4];
#pragma unroll
    for (int q = 0; q < 4; q++)
      xv[q] = (ch[q] < 256) ? xr[q][l] : coord_feat(ch[q] - 256, l);
#pragma unroll
    for (int q = 0; q < 4; q++)
#pragma unroll
      for (int p = 0; p < 6; p++)
        acc[q][p] = fmaf(xv[q], nv[p], acc[q][p]);
  }
#pragma unroll
  for (int q = 0; q < 4; q++)
#pragma unroll
    for (int p = 0; p < 6; p++){
      for (int off = 32; off; off >>= 1) acc[q][p] += __shfl_xor(acc[q][p], off, 64);
    }
  __shared__ float red[4][6][4];
  int wv = tid >> 6;
  if ((tid & 63) == 0){
#pragma unroll
    for (int q = 0; q < 4; q++)
#pragma unroll
      for (int p = 0; p < 6; p++) red[q][p][wv] = acc[q][p];
  }
  __syncthreads();
  if (tid < 24){
    int q = tid / 6, p = tid % 6;
    float s = red[q][p][0] + red[q][p][1] + red[q][p][2] + red[q][p][3];
    cen[(size_t)(p * 4 + n) * 264 + ch[q]] = s;
  }
}

// ---------------- K3: q then qk = q @ W_key, qb = q . b_key ----------------
__global__ __launch_bounds__(256) void k_qk(const float* __restrict__ cen,
                                            const float* __restrict__ W_q, const float* __restrict__ b_q,
                                            const float* __restrict__ W_key, const float* __restrict__ b_key,
                                            float* __restrict__ qk, float* __restrict__ qb){
  int pn = blockIdx.x;
  int tid = threadIdx.x;
  __shared__ float cen_s[264];
  __shared__ float qs[64];
  __shared__ float part[256];
  for (int i = tid; i < 264; i += 256) cen_s[i] = cen[(size_t)pn * 264 + i];
  __syncthreads();
  int o = tid >> 2, pr = tid & 3;
  {
    float a = 0.f;
    int f0 = pr * 66;
    for (int j = 0; j < 66; j++){ int f = f0 + j; a = fmaf(cen_s[f], W_q[o * 264 + f], a); }
    part[tid] = a;
  }
  __syncthreads();
  if (pr == 0) qs[o] = part[tid] + part[tid + 1] + part[tid + 2] + part[tid + 3] + b_q[o];
  __syncthreads();
  for (int c = tid; c < 264; c += 256){
    float a = 0.f;
    for (int oo = 0; oo < 64; oo++) a = fmaf(qs[oo], W_key[oo * 264 + c], a);
    qk[(size_t)pn * 264 + c] = a;
  }
  if (tid < 64) part[tid] = qs[tid] * b_key[tid];
  __syncthreads();
  if (tid == 0){
    float a = 0.f;
    for (int oo = 0; oo < 64; oo++) a += part[oo];
    qb[pn] = a;
  }
}

// ---------------- K4: fused per-pixel kernel + msg-BN-stat partials ----------------
__global__ __launch_bounds__(256) void k_pixel(const float* __restrict__ xp,
                                              const float* __restrict__ p_atts,
                                              const float* __restrict__ W_att, const float* __restrict__ b_att,
                                              const float* __restrict__ W_proj,
                                              const float* __restrict__ qk, const float* __restrict__ qb,
                                              float* __restrict__ out_fdep,
                                              float* __restrict__ s_edge,
                                              float* __restrict__ proj_x,
                                              float* __restrict__ mpart){
  __shared__ float s_watt[256 * 12];   // [c][j]
  __shared__ float s_wproj[256 * 12];  // [c][k] (pad 10->12 with zeros)
  __shared__ float s_qk[256 * 8];      // [c][p] (pad 6->8 with zeros)
  __shared__ float s_qkt[48];          // [p][cc] coord tail
  __shared__ float pacc[4][28][64];
  __shared__ float w0[12], ba[12], qbs[6];
  int n = blockIdx.y;
  int tid = threadIdx.x;
  int wv = tid >> 6, w = tid & 63;
  int l = blockIdx.x * 64 + w;
  for (int i = tid; i < 256 * 12; i += 256){ int c = i / 12, j = i % 12; s_watt[i] = W_att[j * 257 + 1 + c]; }
  for (int i = tid; i < 256 * 12; i += 256){ int c = i / 12, k = i % 12; s_wproj[i] = (k < 10) ? W_proj[k * 256 + c] : 0.f; }
  for (int i = tid; i < 256 * 8; i += 256){ int c = i >> 3, p = i & 7; s_qk[i] = (p < 6) ? qk[((size_t)(p * 4 + n)) * 264 + c] : 0.f; }
  if (tid < 48){ int p = tid >> 3, cc = tid & 7; s_qkt[tid] = qk[((size_t)(p * 4 + n)) * 264 + 256 + cc]; }
  if (tid < 12){ w0[tid] = W_att[tid * 257]; ba[tid] = b_att[tid]; }
  if (tid < 6) qbs[tid] = qb[tid * 4 + n];
  __syncthreads();

  float a[32];
#pragma unroll
  for (int f = 0; f < 32; f++) a[f] = 0.f;
  const float* xpn = xp + (size_t)n * 256 * L + l;
  int c0 = wv * 64;
  for (int cc = 0; cc < 64; cc += 4){
    float xv4[4];
#pragma unroll
    for (int u = 0; u < 4; u++) xv4[u] = xpn[(size_t)(c0 + cc + u) * L];
#pragma unroll
    for (int u = 0; u < 4; u++){
      int c = c0 + cc + u;
      float xv = xv4[u];
      float4 wa0 = *(const float4*)(s_watt + c * 12);
      float4 wa1 = *(const float4*)(s_watt + c * 12 + 4);
      float4 wa2 = *(const float4*)(s_watt + c * 12 + 8);
      float4 wp0 = *(const float4*)(s_wproj + c * 12);
      float4 wp1 = *(const float4*)(s_wproj + c * 12 + 4);
      float4 wp2 = *(const float4*)(s_wproj + c * 12 + 8);
      float4 wq0 = *(const float4*)(s_qk + c * 8);
      float4 wq1 = *(const float4*)(s_qk + c * 8 + 4);
      a[0]  = fmaf(xv, wa0.x, a[0]);  a[1]  = fmaf(xv, wa0.y, a[1]);
      a[2]  = fmaf(xv, wa0.z, a[2]);  a[3]  = fmaf(xv, wa0.w, a[3]);
      a[4]  = fmaf(xv, wa1.x, a[4]);  a[5]  = fmaf(xv, wa1.y, a[5]);
      a[6]  = fmaf(xv, wa1.z, a[6]);  a[7]  = fmaf(xv, wa1.w, a[7]);
      a[8]  = fmaf(xv, wa2.x, a[8]);  a[9]  = fmaf(xv, wa2.y, a[9]);
      a[10] = fmaf(xv, wa2.z, a[10]); a[11] = fmaf(xv, wa2.w, a[11]);
      a[12] = fmaf(xv, wp0.x, a[12]); a[13] = fmaf(xv, wp0.y, a[13]);
      a[14] = fmaf(xv, wp0.z, a[14]); a[15] = fmaf(xv, wp0.w, a[15]);
      a[16] = fmaf(xv, wp1.x, a[16]); a[17] = fmaf(xv, wp1.y, a[17]);
      a[18] = fmaf(xv, wp1.z, a[18]); a[19] = fmaf(xv, wp1.w, a[19]);
      a[20] = fmaf(xv, wp2.x, a[20]); a[21] = fmaf(xv, wp2.y, a[21]);
      a[24] = fmaf(xv, wq0.x, a[24]); a[25] = fmaf(xv, wq0.y, a[25]);
      a[26] = fmaf(xv, wq0.z, a[26]); a[27] = fmaf(xv, wq0.w, a[27]);
      a[28] = fmaf(xv, wq1.x, a[28]); a[29] = fmaf(xv, wq1.y, a[29]);
    }
  }
#pragma unroll
  for (int f = 0; f < 12; f++) pacc[wv][f][w] = a[f];
#pragma unroll
  for (int k = 0; k < 10; k++) pacc[wv][12 + k][w] = a[12 + k];
#pragma unroll
  for (int p = 0; p < 6; p++) pacc[wv][22 + p][w] = a[24 + p];
  __syncthreads();
  for (int idx = tid; idx < 28 * 64; idx += 256){
    int f = idx >> 6, ww = idx & 63;
    pacc[0][f][ww] = pacc[0][f][ww] + pacc[1][f][ww] + pacc[2][f][ww] + pacc[3][f][ww];
  }
  __syncthreads();
  float* se_lds = &pacc[1][0][0];       // 12*64 floats, free after reduce
  if (tid < 64){
    float accA[12], accP[10], accE[6];
#pragma unroll
    for (int j = 0; j < 12; j++) accA[j] = pacc[0][j][w];
#pragma unroll
    for (int k = 0; k < 10; k++) accP[k] = pacc[0][12 + k][w];
#pragma unroll
    for (int p = 0; p < 6; p++) accE[p] = pacc[0][22 + p][w];

    float cf[8];
    { int hh = l >> 6, ww2 = l & 63; const float s = 2.f / 64.f;
      cf[0] = ww2 * s - 1.f; cf[1] = hh * s - 1.f; cf[2] = (ww2 + 1) * s - 1.f; cf[3] = (hh + 1) * s - 1.f;
      cf[4] = (ww2 + 0.5f) * s - 1.f; cf[5] = (hh + 0.5f) * s - 1.f; cf[6] = 1.f / 64.f; cf[7] = 1.f / 64.f; }
    float sat[6];
#pragma unroll
    for (int p = 0; p < 6; p++){
      float e = accE[p] + qbs[p];
#pragma unroll
      for (int cc = 0; cc < 8; cc++) e = fmaf(cf[cc], s_qkt[p * 8 + cc], e);
      float aa = sigmf(e);
      float pa = p_atts[((size_t)(p + 1) * 4 + n) * L + l];
      sat[p] = aa * (1.f - pa);
    }
    const int part_of[12] = {0,1,1,1,1,1,2,3,4,4,5,5};
    float lg[12];
#pragma unroll
    for (int j = 0; j < 12; j++){
      lg[j] = accA[j] + w0[j] * sat[part_of[j]] + ba[j];
      out_fdep[((size_t)n * 12 + j) * L + l] = lg[j];
    }
    const int gs[6] = {0,1,6,7,8,10}, gd[6] = {1,5,1,1,2,2};
    float sm[12];
#pragma unroll
    for (int g = 0; g < 6; g++){
      int s0 = gs[g], d = gd[g];
      float mx = lg[s0];
      for (int t = 1; t < d; t++) mx = fmaxf(mx, lg[s0 + t]);
      float ssum = 0.f;
      for (int t = 0; t < d; t++){ float e2 = expf(lg[s0 + t] - mx); sm[s0 + t] = e2; ssum += e2; }
      float inv = 1.f / ssum;
      for (int t = 0; t < d; t++) sm[s0 + t] *= inv;
    }
#pragma unroll
    for (int e = 0; e < 12; e++){
      float sev = sat[part_of[e]] * sm[e];
      s_edge[((size_t)e * 4 + n) * L + l] = sev;
      se_lds[e * 64 + w] = sev;
    }
#pragma unroll
    for (int k = 0; k < 10; k++) proj_x[((size_t)n * 10 + k) * L + l] = accP[k];
  }
  __syncthreads();
  // msg BN-stat partials: pair = e*10+k, t = se[e]*projx[k]; block-sum over 64 pixels
  {
    int blk = n * 64 + blockIdx.x;       // 0..255
#pragma unroll
    for (int j = 0; j < 30; j++){
      int pair = wv * 30 + j;
      int e = pair / 10, k = pair % 10;
      float t = se_lds[e * 64 + w] * pacc[0][12 + k][w];
      float s1 = t, s2 = t * t;
      for (int off = 32; off; off >>= 1){ s1 += __shfl_xor(s1, off, 64); s2 += __shfl_xor(s2, off, 64); }
      if (w == 0){
        mpart[((size_t)pair * 256 + blk) * 2]     = s1;
        mpart[((size_t)pair * 256 + blk) * 2 + 1] = s2;
      }
    }
  }
}

// ---------------- K7: conv3x3, 2 output rows/thread; inline mpart reduce for BN params ----------------
// block = 256 thr = 4 waves, wave = 2 rows; grid (8 rowblocks, 4 n, 24 (e,h))
__global__ __launch_bounds__(256) void k_conv3(const float* __restrict__ proj_x,
                                               const float* __restrict__ s_edge,
                                               const float* __restrict__ mpart,
                                               const float* __restrict__ g_proj, const float* __restrict__ bt_proj,
                                               const float* __restrict__ p_nodes,
                                               const float* __restrict__ wt2,
                                               float* __restrict__ y,
                                               float* __restrict__ ypart){
  __shared__ float red[4][20];
  __shared__ float scs_s[10], sbs_s[10];
  int rb = blockIdx.x, n = blockIdx.y;
  int e = blockIdx.z >> 1, h = blockIdx.z & 1;
  int v = c_EV[e];
  int tid = threadIdx.x;
  int wv = tid >> 6, w = tid & 63;
  int r0 = rb * 8 + wv * 2;               // output rows r0, r0+1; inputs r0-1 .. r0+2
  float mLm = (w == 0) ? 0.f : 1.f;
  float mRm = (w == 63) ? 0.f : 1.f;

  // inline reduce of msg BN stats (10 entries for this e), waves round-robin
  for (int k = wv; k < 10; k += 4){
    const float* mp = mpart + (size_t)(e * 10 + k) * 512;
    float s1 = mp[w * 2] + mp[(w + 64) * 2] + mp[(w + 128) * 2] + mp[(w + 192) * 2];
    float s2 = mp[w * 2 + 1] + mp[(w + 64) * 2 + 1] + mp[(w + 128) * 2 + 1] + mp[(w + 192) * 2 + 1];
    for (int off = 32; off; off >>= 1){ s1 += __shfl_xor(s1, off, 64); s2 += __shfl_xor(s2, off, 64); }
    if (w == 0){
      float m = s1 / 16384.f, vv = s2 / 16384.f - m * m;
      float istd = rsqrtf(vv + 1e-5f);
      float s = istd * g_proj[k];
      scs_s[k] = s; sbs_s[k] = bt_proj[k] - m * s;
    }
  }
  __syncthreads();
  float scs[10], sbs[10];
#pragma unroll
  for (int k = 0; k < 10; k++){ scs[k] = scs_s[k]; sbs[k] = sbs_s[k]; }

  const size_t enL = ((size_t)e * 4 + n) * L;
  const float* se = s_edge + enL;
  float se4[4];
#pragma unroll
  for (int j = 0; j < 4; j++){
    int rr = r0 - 1 + j;
    se4[j] = (rr >= 0 && rr < 64) ? se[rr * 64 + w] : 0.f;
  }

  float acc0[10], acc1[10];
#pragma unroll
  for (int co = 0; co < 10; co++){ acc0[co] = 0.f; acc1[co] = 0.f; }

  for (int ci = 0; ci < 10; ci++){
    const float* pr = proj_x + ((size_t)n * 10 + ci) * L;
    float mC[4];
#pragma unroll
    for (int j = 0; j < 4; j++){
      int rr = r0 - 1 + j;
      if (rr >= 0 && rr < 64){
        float t = pr[rr * 64 + w] * se4[j];
        mC[j] = fmaxf(fmaf(t, scs[ci], sbs[ci]), 0.f);
      } else mC[j] = 0.f;
    }
    float mL[4], mR[4];
#pragma unroll
    for (int j = 0; j < 4; j++){
      mL[j] = __shfl_up(mC[j], 1) * mLm;
      mR[j] = __shfl_down(mC[j], 1) * mRm;
    }
    const float* wp = wt2 + (ci * 2 + h) * 90;   // wave-uniform -> SGPRs
#pragma unroll
    for (int ky = 0; ky < 3; ky++){
#pragma unroll
      for (int co = 0; co < 10; co++){
        float w0v = wp[(ky * 3 + 0) * 10 + co];
        float w1v = wp[(ky * 3 + 1) * 10 + co];
        float w2v = wp[(ky * 3 + 2) * 10 + co];
        acc0[co] = fmaf(mL[ky], w0v, fmaf(mC[ky], w1v, fmaf(mR[ky], w2v, acc0[co])));
        acc1[co] = fmaf(mL[ky + 1], w0v, fmaf(mC[ky + 1], w1v, fmaf(mR[ky + 1], w2v, acc1[co])));
      }
    }
  }
  for (int ci = 10; ci < 20; ci++){
    const float* pnp = p_nodes + (((size_t)v * 4 + n) * 10 + (ci - 10)) * L;
    float mC[4];
#pragma unroll
    for (int j = 0; j < 4; j++){
      int rr = r0 - 1 + j;
      mC[j] = (rr >= 0 && rr < 64) ? pnp[rr * 64 + w] : 0.f;
    }
    float mL[4], mR[4];
#pragma unroll
    for (int j = 0; j < 4; j++){
      mL[j] = __shfl_up(mC[j], 1) * mLm;
      mR[j] = __shfl_down(mC[j], 1) * mRm;
    }
    const float* wp = wt2 + (ci * 2 + h) * 90;
#pragma unroll
    for (int ky = 0; ky < 3; ky++){
#pragma unroll
      for (int co = 0; co < 10; co++){
        float w0v = wp[(ky * 3 + 0) * 10 + co];
        float w1v = wp[(ky * 3 + 1) * 10 + co];
        float w2v = wp[(ky * 3 + 2) * 10 + co];
        acc0[co] = fmaf(mL[ky], w0v, fmaf(mC[ky], w1v, fmaf(mR[ky], w2v, acc0[co])));
        acc1[co] = fmaf(mL[ky + 1], w0v, fmaf(mC[ky + 1], w1v, fmaf(mR[ky + 1], w2v, acc1[co])));
      }
    }
  }

  int ch0 = h * 10;
#pragma unroll
  for (int co = 0; co < 10; co++){
    size_t base = enL * 20 + ((size_t)(ch0 + co)) * L;
    y[base + r0 * 64 + w] = acc0[co];
    y[base + (r0 + 1) * 64 + w] = acc1[co];
  }

  // per-block BN partials for y
#pragma unroll
  for (int co = 0; co < 10; co++){
    float s1 = acc0[co] + acc1[co];
    float s2 = acc0[co] * acc0[co] + acc1[co] * acc1[co];
    for (int off = 32; off; off >>= 1){ s1 += __shfl_xor(s1, off, 64); s2 += __shfl_xor(s2, off, 64); }
    if (w == 0){ red[wv][2 * co] = s1; red[wv][2 * co + 1] = s2; }
  }
  __syncthreads();
  if (tid < 20){
    int co = tid >> 1, which = tid & 1;
    float s = red[0][tid] + red[1][tid] + red[2][tid] + red[3][tid];
    ypart[(((size_t)(e * 20 + ch0 + co) * 32) + n * 8 + rb) * 2 + which] = s;
  }
}

// ---------------- K9: fused mout + gather + GRU; inline ypart reduce; cnm-stat partials ----------------
__global__ __launch_bounds__(256) void k_mout_gru(const float* __restrict__ y,
                                                  const float* __restrict__ ypart,
                                                  const float* __restrict__ g_rel1, const float* __restrict__ bt_rel1,
                                                  const float* __restrict__ W_rel2, const float* __restrict__ b_rel2,
                                                  const float* __restrict__ p_nodes,
                                                  const float* __restrict__ Wg, const float* __restrict__ bg,
                                                  const float* __restrict__ Wc,
                                                  float* __restrict__ cnm, float* __restrict__ zbuf,
                                                  float* __restrict__ cpart){
  int i = blockIdx.z, n = blockIdx.y;
  int tid = threadIdx.x;
  int l = blockIdx.x * 256 + tid;
  __shared__ float w2[200], wc[200], wg[40], bgs[2];
  __shared__ float sc[5][20], sb[5][20];
  __shared__ float red[4][20];
  int ne = c_INOFF[i + 1] - c_INOFF[i];
  for (int t = tid; t < 200; t += 256){ w2[t] = W_rel2[t]; wc[t] = Wc[i * 200 + t]; }
  if (tid < 40) wg[tid] = Wg[i * 40 + tid];
  if (tid < 2) bgs[tid] = bg[i * 2 + tid];
  if (tid < ne * 20){
    int ei = tid / 20, c = tid % 20;
    int e = c_INE[c_INOFF[i] + ei];
    int ec = e * 20 + c;
    float s1 = 0.f, s2 = 0.f;
#pragma unroll 8
    for (int t = 0; t < 32; t++){
      s1 += ypart[((size_t)ec * 32 + t) * 2];
      s2 += ypart[((size_t)ec * 32 + t) * 2 + 1];
    }
    float m = s1 / 16384.f, vv = s2 / 16384.f - m * m;
    float istd = rsqrtf(vv + 1e-5f);
    float s = istd * g_rel1[c];
    sc[ei][c] = s; sb[ei][c] = bt_rel1[c] - m * s;
  }
  __syncthreads();
  float m[10];
#pragma unroll
  for (int k = 0; k < 10; k++) m[k] = 0.f;
  for (int ei = 0; ei < ne; ei++){
    int e = c_INE[c_INOFF[i] + ei];
    float z[20];
#pragma unroll
    for (int c = 0; c < 20; c++){
      float t = y[(((size_t)e * 4 + n) * 20 + c) * L + l];
      z[c] = fmaxf(t * sc[ei][c] + sb[ei][c], 0.f);
    }
#pragma unroll
    for (int k = 0; k < 10; k++){
      float a = b_rel2[k];
#pragma unroll
      for (int c = 0; c < 20; c++) a = fmaf(w2[k * 20 + c], z[c], a);
      m[k] += sigmf(a);
    }
  }
  float h[10];
#pragma unroll
  for (int k = 0; k < 10; k++) h[k] = p_nodes[(((size_t)(i + 1) * 4 + n) * 10 + k) * L + l];
  float g0 = bgs[0], g1 = bgs[1];
#pragma unroll
  for (int k = 0; k < 10; k++){
    g0 = fmaf(wg[k], m[k], g0); g0 = fmaf(wg[10 + k], h[k], g0);
    g1 = fmaf(wg[20 + k], m[k], g1); g1 = fmaf(wg[30 + k], h[k], g1);
  }
  float r = sigmf(g0), zz = sigmf(g1);
  zbuf[((size_t)i * 4 + n) * L + l] = zz;
  float cv[10];
#pragma unroll
  for (int k = 0; k < 10; k++){
    float a = 0.f;
#pragma unroll
    for (int c = 0; c < 10; c++){
      a = fmaf(wc[k * 20 + c], m[c], a);
      a = fmaf(wc[k * 20 + 10 + c], r * h[c], a);
    }
    cv[k] = a;
    cnm[(((size_t)i * 4 + n) * 10 + k) * L + l] = a;
  }
  int wv = tid >> 6, w = tid & 63;
#pragma unroll
  for (int k = 0; k < 10; k++){
    float s1 = cv[k], s2 = cv[k] * cv[k];
    for (int off = 32; off; off >>= 1){ s1 += __shfl_xor(s1, off, 64); s2 += __shfl_xor(s2, off, 64); }
    if (w == 0){ red[wv][2 * k] = s1; red[wv][2 * k + 1] = s2; }
  }
  __syncthreads();
  if (tid < 20){
    float s = red[0][tid] + red[1][tid] + red[2][tid] + red[3][tid];
    int k = tid >> 1, which = tid & 1;
    cpart[(((size_t)(i * 10 + k) * 64) + n * 16 + blockIdx.x) * 2 + which] = s;
  }
}

// ---------------- K13: final node update + part-0 copy; inline cpart reduce ----------------
__global__ __launch_bounds__(256) void k_out(const float* __restrict__ cnm, const float* __restrict__ zbuf,
                                             const float* __restrict__ p_nodes,
                                             const float* __restrict__ cpart,
                                             const float* __restrict__ g_can, const float* __restrict__ bt_can,
                                             float* __restrict__ out){
  int tid = threadIdx.x;
  int idx = blockIdx.x * 256 + tid;
  const int NODE = 4 * 10 * L;
  if (idx < NODE){ out[idx] = p_nodes[idx]; return; }   // whole block is in copy region (NODE % 256 == 0)
  int j = idx - NODE;
  int l = j & (L - 1); int r = j >> 12;
  int k = r % 10; r /= 10; int n = r & 3; int i = r >> 2;
  int ik = i * 10 + k;                                   // uniform across block
  __shared__ float smu, sistd;
  if (tid < 64){
    float s1 = cpart[((size_t)ik * 64 + tid) * 2];
    float s2 = cpart[((size_t)ik * 64 + tid) * 2 + 1];
    for (int off = 32; off; off >>= 1){ s1 += __shfl_xor(s1, off, 64); s2 += __shfl_xor(s2, off, 64); }
    if (tid == 0){
      float m = s1 / 16384.f, v = s2 / 16384.f - m * m;
      smu = m; sistd = rsqrtf(v + 1e-5f);
    }
  }
  __syncthreads();
  float c = cnm[j];
  float cn = (c - smu) * sistd * g_can[ik] + bt_can[ik];
  cn = cn > 0.f ? cn : 0.01f * cn;
  float z = zbuf[((size_t)i * 4 + n) * L + l];
  float h = p_nodes[idx];
  out[idx] = (1.f - z) * h + z * cn;
}

extern "C" void kernel_launch(void* const* d_in, const int* in_sizes, int n_in,
                              void* d_out, int out_size, void* d_ws, size_t ws_size,
                              hipStream_t stream){
  (void)in_sizes; (void)n_in; (void)out_size; (void)ws_size;
  const float* xp      = (const float*)d_in[0];
  const float* p_nodes = (const float*)d_in[1];
  const float* p_atts  = (const float*)d_in[2];
  const float* W_key   = (const float*)d_in[3];
  const float* b_key   = (const float*)d_in[4];
  const float* W_q     = (const float*)d_in[5];
  const float* b_q     = (const float*)d_in[6];
  const float* W_att   = (const float*)d_in[7];
  const float* b_att   = (const float*)d_in[8];
  const float* W_proj  = (const float*)d_in[9];
  const float* g_proj  = (const float*)d_in[10];
  const float* bt_proj = (const float*)d_in[11];
  const float* W_rel1  = (const float*)d_in[12];
  const float* g_rel1  = (const float*)d_in[13];
  const float* bt_rel1 = (const float*)d_in[14];
  const float* W_rel2  = (const float*)d_in[15];
  const float* b_rel2  = (const float*)d_in[16];
  const float* Wg      = (const float*)d_in[17];
  const float* bg      = (const float*)d_in[18];
  const float* Wc      = (const float*)d_in[19];
  const float* g_can   = (const float*)d_in[20];
  const float* bt_can  = (const float*)d_in[21];

  float* out      = (float*)d_out;
  float* fdep_out = out + (size_t)7 * 4 * 10 * L;   // xp_new first, then fdep_att

  float* w = (float*)d_ws;
  size_t off = 0;
  auto alloc = [&](size_t nf){ float* p = w + off; off += nf; return p; };
  float* norm    = alloc((size_t)6 * 4 * L);
  float* cen     = alloc(6 * 4 * 264);
  float* qk      = alloc(6 * 4 * 264);
  float* qb      = alloc(24);
  float* wt2     = alloc(3600);
  float* proj_x  = alloc((size_t)4 * 10 * L);
  float* s_edge  = alloc((size_t)12 * 4 * L);
  float* mpart   = alloc(120 * 256 * 2);
  float* ybuf    = alloc((size_t)12 * 4 * 20 * L);
  float* ypart   = alloc(240 * 32 * 2);
  float* cpart   = alloc(60 * 64 * 2);
  float* cnm     = alloc((size_t)6 * 4 * 10 * L);
  float* zbuf    = alloc((size_t)6 * 4 * L);

  k_softmax_norm<<<25, 256, 0, stream>>>(p_atts, norm, W_rel1, wt2);
  { dim3 g(66, 4); k_centroid<<<g, 256, 0, stream>>>(xp, norm, cen); }
  k_qk<<<24, 256, 0, stream>>>(cen, W_q, b_q, W_key, b_key, qk, qb);
  { dim3 g(64, 4); k_pixel<<<g, 256, 0, stream>>>(xp, p_atts, W_att, b_att, W_proj, qk, qb, fdep_out, s_edge, proj_x, mpart); }
  { dim3 g(8, 4, 24); k_conv3<<<g, 256, 0, stream>>>(proj_x, s_edge, mpart, g_proj, bt_proj, p_nodes, wt2, ybuf, ypart); }
  { dim3 g(16, 4, 6); k_mout_gru<<<g, 256, 0, stream>>>(ybuf, ypart, g_rel1, bt_rel1, W_rel2, b_rel2,
                                                        p_nodes, Wg, bg, Wc, cnm, zbuf, cpart); }
  k_out<<<(7 * 4 * 10 * L) / 256, 256, 0, stream>>>(cnm, zbuf, p_nodes, cpart, g_can, bt_can, out);
}

// Round 15
// 138.295 us; speedup vs baseline: 1.0607x; 1.0356x over previous
//
#include <hip/hip_runtime.h>
#include <math.h>

#define L 4096

// edge tables
__constant__ int c_EV[12]   = {1,0,2,3,4,5,1,1,1,5,1,4};      // dest v of edge e
__constant__ int c_INOFF[7] = {0,1,6,7,8,10,12};              // incoming-edge offsets per v
__constant__ int c_INE[12]  = {1, 0,6,7,8,10, 2, 3, 4,11, 5,9}; // incoming edge ids

__device__ inline float sigmf(float x){ return 1.f/(1.f+expf(-x)); }

// ---------------- K1: softmax over L of p_att rows (blocks 0..23) + W_rel1 repack (block 24) ----------------
__global__ __launch_bounds__(256) void k_softmax_norm(const float* __restrict__ p_atts,
                                                      float* __restrict__ norm,
                                                      const float* __restrict__ W_rel1,
                                                      float* __restrict__ wt2){
  int tid = threadIdx.x;
  if (blockIdx.x == 24){
    // wt2[ci][h][k][co10]: 90-dword SGPR slices
    for (int i = tid; i < 3600; i += 256){
      int co = i % 10; int t = i / 10;
      int k = t % 9; t /= 9;
      int h = t & 1; int ci = t >> 1;
      wt2[i] = W_rel1[(((h * 10 + co) * 20) + ci) * 9 + k];
    }
    return;
  }
  int pn = blockIdx.x;                       // p*4+n
  const float* src = p_atts + (size_t)(pn + 4) * L;   // (p+1)*4+n
  float* dst = norm + (size_t)pn * L;
  __shared__ float red[256];
  float m = -1e30f;
  for (int l = tid; l < L; l += 256) m = fmaxf(m, src[l]);
  red[tid] = m; __syncthreads();
  for (int s = 128; s; s >>= 1){ if (tid < s) red[tid] = fmaxf(red[tid], red[tid+s]); __syncthreads(); }
  m = red[0]; __syncthreads();
  float sum = 0.f;
  for (int l = tid; l < L; l += 256) sum += expf(src[l] - m);
  red[tid] = sum; __syncthreads();
  for (int s = 128; s; s >>= 1){ if (tid < s) red[tid] += red[tid+s]; __syncthreads(); }
  float inv = 1.f / red[0];
  for (int l = tid; l < L; l += 256) dst[l] = expf(src[l] - m) * inv;
}

__device__ inline float coord_feat(int cc, int l){
  int h = l >> 6, w = l & 63;
  const float s = 2.f / 64.f;
  switch (cc){
    case 0: return w * s - 1.f;
    case 1: return h * s - 1.f;
    case 2: return (w + 1) * s - 1.f;
    case 3: return (h + 1) * s - 1.f;
    case 4: return (w + 0.5f) * s - 1.f;
    case 5: return (h + 0.5f) * s - 1.f;
    default: return 1.f / 64.f;
  }
}

// ---------------- K2: centroids — 2 channels/block, norm loaded once per pixel ----------------
__global__ __launch_bounds__(256) void k_centroid(const float* __restrict__ xp,
                                                  const float* __restrict__ norm,
                                                  float* __restrict__ cen){
  int c0 = blockIdx.x;         // 0..131 -> channels c0 and c0+132
  int c1 = c0 + 132;
  int n = blockIdx.y;          // 0..3
  int tid = threadIdx.x;
  float acc[2][6];
#pragma unroll
  for (int q = 0; q < 2; q++)
#pragma unroll
    for (int p = 0; p < 6; p++) acc[q][p] = 0.f;
  const float* nr0 = norm + (size_t)n * L;
  const float* xr0 = xp + ((size_t)n * 256 + c0) * L;
  const float* xr1 = (c1 < 256) ? xp + ((size_t)n * 256 + c1) * L : nullptr;
  int cc1 = c1 - 256;
  for (int l = tid; l < L; l += 256){
    float nv[6];
#pragma unroll
    for (int p = 0; p < 6; p++) nv[p] = nr0[(size_t)p * 4 * L + l];
    float x0 = xr0[l];
    float x1 = (c1 < 256) ? xr1[l] : coord_feat(cc1, l);
#pragma unroll
    for (int p = 0; p < 6; p++){
      acc[0][p] = fmaf(x0, nv[p], acc[0][p]);
      acc[1][p] = fmaf(x1, nv[p], acc[1][p]);
    }
  }
#pragma unroll
  for (int q = 0; q < 2; q++)
#pragma unroll
    for (int p = 0; p < 6; p++){
      for (int off = 32; off; off >>= 1) acc[q][p] += __shfl_xor(acc[q][p], off, 64);
    }
  __shared__ float red[2][6][4];
  int wv = tid >> 6;
  if ((tid & 63) == 0){
#pragma unroll
    for (int q = 0; q < 2; q++)
#pragma unroll
      for (int p = 0; p < 6; p++) red[q][p][wv] = acc[q][p];
  }
  __syncthreads();
  if (tid < 12){
    int q = tid / 6, p = tid % 6;
    float s = red[q][p][0] + red[q][p][1] + red[q][p][2] + red[q][p][3];
    cen[(size_t)(p * 4 + n) * 264 + (q ? c1 : c0)] = s;
  }
}

// ---------------- K3: q then qk = q @ W_key, qb = q . b_key ----------------
__global__ __launch_bounds__(256) void k_qk(const float* __restrict__ cen,
                                            const float* __restrict__ W_q, const float* __restrict__ b_q,
                                            const float* __restrict__ W_key, const float* __restrict__ b_key,
                                            float* __restrict__ qk, float* __restrict__ qb){
  int pn = blockIdx.x;
  int tid = threadIdx.x;
  __shared__ float cen_s[264];
  __shared__ float qs[64];
  __shared__ float part[256];
  for (int i = tid; i < 264; i += 256) cen_s[i] = cen[(size_t)pn * 264 + i];
  __syncthreads();
  int o = tid >> 2, pr = tid & 3;
  {
    float a = 0.f;
    int f0 = pr * 66;
    for (int j = 0; j < 66; j++){ int f = f0 + j; a = fmaf(cen_s[f], W_q[o * 264 + f], a); }
    part[tid] = a;
  }
  __syncthreads();
  if (pr == 0) qs[o] = part[tid] + part[tid + 1] + part[tid + 2] + part[tid + 3] + b_q[o];
  __syncthreads();
  for (int c = tid; c < 264; c += 256){
    float a = 0.f;
    for (int oo = 0; oo < 64; oo++) a = fmaf(qs[oo], W_key[oo * 264 + c], a);
    qk[(size_t)pn * 264 + c] = a;
  }
  if (tid < 64) part[tid] = qs[tid] * b_key[tid];
  __syncthreads();
  if (tid == 0){
    float a = 0.f;
    for (int oo = 0; oo < 64; oo++) a += part[oo];
    qb[pn] = a;
  }
}

// ---------------- K4: fused per-pixel kernel + msg-BN-stat partials ----------------
__global__ __launch_bounds__(256) void k_pixel(const float* __restrict__ xp,
                                              const float* __restrict__ p_atts,
                                              const float* __restrict__ W_att, const float* __restrict__ b_att,
                                              const float* __restrict__ W_proj,
                                              const float* __restrict__ qk, const float* __restrict__ qb,
                                              float* __restrict__ out_fdep,
                                              float* __restrict__ s_edge,
                                              float* __restrict__ proj_x,
                                              float* __restrict__ mpart){
  __shared__ float s_watt[256 * 12];   // [c][j]
  __shared__ float s_wproj[256 * 12];  // [c][k] (pad 10->12 with zeros)
  __shared__ float s_qk[256 * 8];      // [c][p] (pad 6->8 with zeros)
  __shared__ float s_qkt[48];          // [p][cc] coord tail
  __shared__ float pacc[4][28][64];
  __shared__ float w0[12], ba[12], qbs[6];
  int n = blockIdx.y;
  int tid = threadIdx.x;
  int wv = tid >> 6, w = tid & 63;
  int l = blockIdx.x * 64 + w;
  for (int i = tid; i < 256 * 12; i += 256){ int c = i / 12, j = i % 12; s_watt[i] = W_att[j * 257 + 1 + c]; }
  for (int i = tid; i < 256 * 12; i += 256){ int c = i / 12, k = i % 12; s_wproj[i] = (k < 10) ? W_proj[k * 256 + c] : 0.f; }
  for (int i = tid; i < 256 * 8; i += 256){ int c = i >> 3, p = i & 7; s_qk[i] = (p < 6) ? qk[((size_t)(p * 4 + n)) * 264 + c] : 0.f; }
  if (tid < 48){ int p = tid >> 3, cc = tid & 7; s_qkt[tid] = qk[((size_t)(p * 4 + n)) * 264 + 256 + cc]; }
  if (tid < 12){ w0[tid] = W_att[tid * 257]; ba[tid] = b_att[tid]; }
  if (tid < 6) qbs[tid] = qb[tid * 4 + n];
  __syncthreads();

  float a[32];
#pragma unroll
  for (int f = 0; f < 32; f++) a[f] = 0.f;
  const float* xpn = xp + (size_t)n * 256 * L + l;
  int c0 = wv * 64;
  for (int cc = 0; cc < 64; cc += 4){
    float xv4[4];
#pragma unroll
    for (int u = 0; u < 4; u++) xv4[u] = xpn[(size_t)(c0 + cc + u) * L];
#pragma unroll
    for (int u = 0; u < 4; u++){
      int c = c0 + cc + u;
      float xv = xv4[u];
      float4 wa0 = *(const float4*)(s_watt + c * 12);
      float4 wa1 = *(const float4*)(s_watt + c * 12 + 4);
      float4 wa2 = *(const float4*)(s_watt + c * 12 + 8);
      float4 wp0 = *(const float4*)(s_wproj + c * 12);
      float4 wp1 = *(const float4*)(s_wproj + c * 12 + 4);
      float4 wp2 = *(const float4*)(s_wproj + c * 12 + 8);
      float4 wq0 = *(const float4*)(s_qk + c * 8);
      float4 wq1 = *(const float4*)(s_qk + c * 8 + 4);
      a[0]  = fmaf(xv, wa0.x, a[0]);  a[1]  = fmaf(xv, wa0.y, a[1]);
      a[2]  = fmaf(xv, wa0.z, a[2]);  a[3]  = fmaf(xv, wa0.w, a[3]);
      a[4]  = fmaf(xv, wa1.x, a[4]);  a[5]  = fmaf(xv, wa1.y, a[5]);
      a[6]  = fmaf(xv, wa1.z, a[6]);  a[7]  = fmaf(xv, wa1.w, a[7]);
      a[8]  = fmaf(xv, wa2.x, a[8]);  a[9]  = fmaf(xv, wa2.y, a[9]);
      a[10] = fmaf(xv, wa2.z, a[10]); a[11] = fmaf(xv, wa2.w, a[11]);
      a[12] = fmaf(xv, wp0.x, a[12]); a[13] = fmaf(xv, wp0.y, a[13]);
      a[14] = fmaf(xv, wp0.z, a[14]); a[15] = fmaf(xv, wp0.w, a[15]);
      a[16] = fmaf(xv, wp1.x, a[16]); a[17] = fmaf(xv, wp1.y, a[17]);
      a[18] = fmaf(xv, wp1.z, a[18]); a[19] = fmaf(xv, wp1.w, a[19]);
      a[20] = fmaf(xv, wp2.x, a[20]); a[21] = fmaf(xv, wp2.y, a[21]);
      a[24] = fmaf(xv, wq0.x, a[24]); a[25] = fmaf(xv, wq0.y, a[25]);
      a[26] = fmaf(xv, wq0.z, a[26]); a[27] = fmaf(xv, wq0.w, a[27]);
      a[28] = fmaf(xv, wq1.x, a[28]); a[29] = fmaf(xv, wq1.y, a[29]);
    }
  }
#pragma unroll
  for (int f = 0; f < 12; f++) pacc[wv][f][w] = a[f];
#pragma unroll
  for (int k = 0; k < 10; k++) pacc[wv][12 + k][w] = a[12 + k];
#pragma unroll
  for (int p = 0; p < 6; p++) pacc[wv][22 + p][w] = a[24 + p];
  __syncthreads();
  for (int idx = tid; idx < 28 * 64; idx += 256){
    int f = idx >> 6, ww = idx & 63;
    pacc[0][f][ww] = pacc[0][f][ww] + pacc[1][f][ww] + pacc[2][f][ww] + pacc[3][f][ww];
  }
  __syncthreads();
  float* se_lds = &pacc[1][0][0];       // 12*64 floats, free after reduce
  if (tid < 64){
    float accA[12], accP[10], accE[6];
#pragma unroll
    for (int j = 0; j < 12; j++) accA[j] = pacc[0][j][w];
#pragma unroll
    for (int k = 0; k < 10; k++) accP[k] = pacc[0][12 + k][w];
#pragma unroll
    for (int p = 0; p < 6; p++) accE[p] = pacc[0][22 + p][w];

    float cf[8];
    { int hh = l >> 6, ww2 = l & 63; const float s = 2.f / 64.f;
      cf[0] = ww2 * s - 1.f; cf[1] = hh * s - 1.f; cf[2] = (ww2 + 1) * s - 1.f; cf[3] = (hh + 1) * s - 1.f;
      cf[4] = (ww2 + 0.5f) * s - 1.f; cf[5] = (hh + 0.5f) * s - 1.f; cf[6] = 1.f / 64.f; cf[7] = 1.f / 64.f; }
    float sat[6];
#pragma unroll
    for (int p = 0; p < 6; p++){
      float e = accE[p] + qbs[p];
#pragma unroll
      for (int cc = 0; cc < 8; cc++) e = fmaf(cf[cc], s_qkt[p * 8 + cc], e);
      float aa = sigmf(e);
      float pa = p_atts[((size_t)(p + 1) * 4 + n) * L + l];
      sat[p] = aa * (1.f - pa);
    }
    const int part_of[12] = {0,1,1,1,1,1,2,3,4,4,5,5};
    float lg[12];
#pragma unroll
    for (int j = 0; j < 12; j++){
      lg[j] = accA[j] + w0[j] * sat[part_of[j]] + ba[j];
      out_fdep[((size_t)n * 12 + j) * L + l] = lg[j];
    }
    const int gs[6] = {0,1,6,7,8,10}, gd[6] = {1,5,1,1,2,2};
    float sm[12];
#pragma unroll
    for (int g = 0; g < 6; g++){
      int s0 = gs[g], d = gd[g];
      float mx = lg[s0];
      for (int t = 1; t < d; t++) mx = fmaxf(mx, lg[s0 + t]);
      float ssum = 0.f;
      for (int t = 0; t < d; t++){ float e2 = expf(lg[s0 + t] - mx); sm[s0 + t] = e2; ssum += e2; }
      float inv = 1.f / ssum;
      for (int t = 0; t < d; t++) sm[s0 + t] *= inv;
    }
#pragma unroll
    for (int e = 0; e < 12; e++){
      float sev = sat[part_of[e]] * sm[e];
      s_edge[((size_t)e * 4 + n) * L + l] = sev;
      se_lds[e * 64 + w] = sev;
    }
#pragma unroll
    for (int k = 0; k < 10; k++) proj_x[((size_t)n * 10 + k) * L + l] = accP[k];
  }
  __syncthreads();
  // msg BN-stat partials: pair = e*10+k, t = se[e]*projx[k]; block-sum over 64 pixels
  {
    int blk = n * 64 + blockIdx.x;       // 0..255
#pragma unroll
    for (int j = 0; j < 30; j++){
      int pair = wv * 30 + j;
      int e = pair / 10, k = pair % 10;
      float t = se_lds[e * 64 + w] * pacc[0][12 + k][w];
      float s1 = t, s2 = t * t;
      for (int off = 32; off; off >>= 1){ s1 += __shfl_xor(s1, off, 64); s2 += __shfl_xor(s2, off, 64); }
      if (w == 0){
        mpart[((size_t)pair * 256 + blk) * 2]     = s1;
        mpart[((size_t)pair * 256 + blk) * 2 + 1] = s2;
      }
    }
  }
}

// ---------------- K7: conv3x3, 2 output rows/thread; inline mpart reduce for BN params ----------------
// block = 256 thr = 4 waves, wave = 2 rows; grid (8 rowblocks, 4 n, 24 (e,h))
__global__ __launch_bounds__(256) void k_conv3(const float* __restrict__ proj_x,
                                               const float* __restrict__ s_edge,
                                               const float* __restrict__ mpart,
                                               const float* __restrict__ g_proj, const float* __restrict__ bt_proj,
                                               const float* __restrict__ p_nodes,
                                               const float* __restrict__ wt2,
                                               float* __restrict__ y,
                                               float* __restrict__ ypart){
  __shared__ float red[4][20];
  __shared__ float scs_s[10], sbs_s[10];
  int rb = blockIdx.x, n = blockIdx.y;
  int e = blockIdx.z >> 1, h = blockIdx.z & 1;
  int v = c_EV[e];
  int tid = threadIdx.x;
  int wv = tid >> 6, w = tid & 63;
  int r0 = rb * 8 + wv * 2;               // output rows r0, r0+1; inputs r0-1 .. r0+2
  float mLm = (w == 0) ? 0.f : 1.f;
  float mRm = (w == 63) ? 0.f : 1.f;

  // inline reduce of msg BN stats (10 entries for this e), waves round-robin
  for (int k = wv; k < 10; k += 4){
    const float* mp = mpart + (size_t)(e * 10 + k) * 512;
    float s1 = mp[w * 2] + mp[(w + 64) * 2] + mp[(w + 128) * 2] + mp[(w + 192) * 2];
    float s2 = mp[w * 2 + 1] + mp[(w + 64) * 2 + 1] + mp[(w + 128) * 2 + 1] + mp[(w + 192) * 2 + 1];
    for (int off = 32; off; off >>= 1){ s1 += __shfl_xor(s1, off, 64); s2 += __shfl_xor(s2, off, 64); }
    if (w == 0){
      float m = s1 / 16384.f, vv = s2 / 16384.f - m * m;
      float istd = rsqrtf(vv + 1e-5f);
      float s = istd * g_proj[k];
      scs_s[k] = s; sbs_s[k] = bt_proj[k] - m * s;
    }
  }
  __syncthreads();
  float scs[10], sbs[10];
#pragma unroll
  for (int k = 0; k < 10; k++){ scs[k] = scs_s[k]; sbs[k] = sbs_s[k]; }

  const size_t enL = ((size_t)e * 4 + n) * L;
  const float* se = s_edge + enL;
  float se4[4];
#pragma unroll
  for (int j = 0; j < 4; j++){
    int rr = r0 - 1 + j;
    se4[j] = (rr >= 0 && rr < 64) ? se[rr * 64 + w] : 0.f;
  }

  float acc0[10], acc1[10];
#pragma unroll
  for (int co = 0; co < 10; co++){ acc0[co] = 0.f; acc1[co] = 0.f; }

  for (int ci = 0; ci < 10; ci++){
    const float* pr = proj_x + ((size_t)n * 10 + ci) * L;
    float mC[4];
#pragma unroll
    for (int j = 0; j < 4; j++){
      int rr = r0 - 1 + j;
      if (rr >= 0 && rr < 64){
        float t = pr[rr * 64 + w] * se4[j];
        mC[j] = fmaxf(fmaf(t, scs[ci], sbs[ci]), 0.f);
      } else mC[j] = 0.f;
    }
    float mL[4], mR[4];
#pragma unroll
    for (int j = 0; j < 4; j++){
      mL[j] = __shfl_up(mC[j], 1) * mLm;
      mR[j] = __shfl_down(mC[j], 1) * mRm;
    }
    const float* wp = wt2 + (ci * 2 + h) * 90;   // wave-uniform -> SGPRs
#pragma unroll
    for (int ky = 0; ky < 3; ky++){
#pragma unroll
      for (int co = 0; co < 10; co++){
        float w0v = wp[(ky * 3 + 0) * 10 + co];
        float w1v = wp[(ky * 3 + 1) * 10 + co];
        float w2v = wp[(ky * 3 + 2) * 10 + co];
        acc0[co] = fmaf(mL[ky], w0v, fmaf(mC[ky], w1v, fmaf(mR[ky], w2v, acc0[co])));
        acc1[co] = fmaf(mL[ky + 1], w0v, fmaf(mC[ky + 1], w1v, fmaf(mR[ky + 1], w2v, acc1[co])));
      }
    }
  }
  for (int ci = 10; ci < 20; ci++){
    const float* pnp = p_nodes + (((size_t)v * 4 + n) * 10 + (ci - 10)) * L;
    float mC[4];
#pragma unroll
    for (int j = 0; j < 4; j++){
      int rr = r0 - 1 + j;
      mC[j] = (rr >= 0 && rr < 64) ? pnp[rr * 64 + w] : 0.f;
    }
    float mL[4], mR[4];
#pragma unroll
    for (int j = 0; j < 4; j++){
      mL[j] = __shfl_up(mC[j], 1) * mLm;
      mR[j] = __shfl_down(mC[j], 1) * mRm;
    }
    const float* wp = wt2 + (ci * 2 + h) * 90;
#pragma unroll
    for (int ky = 0; ky < 3; ky++){
#pragma unroll
      for (int co = 0; co < 10; co++){
        float w0v = wp[(ky * 3 + 0) * 10 + co];
        float w1v = wp[(ky * 3 + 1) * 10 + co];
        float w2v = wp[(ky * 3 + 2) * 10 + co];
        acc0[co] = fmaf(mL[ky], w0v, fmaf(mC[ky], w1v, fmaf(mR[ky], w2v, acc0[co])));
        acc1[co] = fmaf(mL[ky + 1], w0v, fmaf(mC[ky + 1], w1v, fmaf(mR[ky + 1], w2v, acc1[co])));
      }
    }
  }

  int ch0 = h * 10;
#pragma unroll
  for (int co = 0; co < 10; co++){
    size_t base = enL * 20 + ((size_t)(ch0 + co)) * L;
    y[base + r0 * 64 + w] = acc0[co];
    y[base + (r0 + 1) * 64 + w] = acc1[co];
  }

  // per-block BN partials for y
#pragma unroll
  for (int co = 0; co < 10; co++){
    float s1 = acc0[co] + acc1[co];
    float s2 = acc0[co] * acc0[co] + acc1[co] * acc1[co];
    for (int off = 32; off; off >>= 1){ s1 += __shfl_xor(s1, off, 64); s2 += __shfl_xor(s2, off, 64); }
    if (w == 0){ red[wv][2 * co] = s1; red[wv][2 * co + 1] = s2; }
  }
  __syncthreads();
  if (tid < 20){
    int co = tid >> 1, which = tid & 1;
    float s = red[0][tid] + red[1][tid] + red[2][tid] + red[3][tid];
    ypart[(((size_t)(e * 20 + ch0 + co) * 32) + n * 8 + rb) * 2 + which] = s;
  }
}

// ---------------- K9: fused mout + gather + GRU; inline ypart reduce; cnm-stat partials ----------------
__global__ __launch_bounds__(256) void k_mout_gru(const float* __restrict__ y,
                                                  const float* __restrict__ ypart,
                                                  const float* __restrict__ g_rel1, const float* __restrict__ bt_rel1,
                                                  const float* __restrict__ W_rel2, const float* __restrict__ b_rel2,
                                                  const float* __restrict__ p_nodes,
                                                  const float* __restrict__ Wg, const float* __restrict__ bg,
                                                  const float* __restrict__ Wc,
                                                  float* __restrict__ cnm, float* __restrict__ zbuf,
                                                  float* __restrict__ cpart){
  int i = blockIdx.z, n = blockIdx.y;
  int tid = threadIdx.x;
  int l = blockIdx.x * 256 + tid;
  __shared__ float w2[200], wc[200], wg[40], bgs[2];
  __shared__ float sc[5][20], sb[5][20];
  __shared__ float red[4][20];
  int ne = c_INOFF[i + 1] - c_INOFF[i];
  for (int t = tid; t < 200; t += 256){ w2[t] = W_rel2[t]; wc[t] = Wc[i * 200 + t]; }
  if (tid < 40) wg[tid] = Wg[i * 40 + tid];
  if (tid < 2) bgs[tid] = bg[i * 2 + tid];
  if (tid < ne * 20){
    int ei = tid / 20, c = tid % 20;
    int e = c_INE[c_INOFF[i] + ei];
    int ec = e * 20 + c;
    float s1 = 0.f, s2 = 0.f;
#pragma unroll 8
    for (int t = 0; t < 32; t++){
      s1 += ypart[((size_t)ec * 32 + t) * 2];
      s2 += ypart[((size_t)ec * 32 + t) * 2 + 1];
    }
    float m = s1 / 16384.f, vv = s2 / 16384.f - m * m;
    float istd = rsqrtf(vv + 1e-5f);
    float s = istd * g_rel1[c];
    sc[ei][c] = s; sb[ei][c] = bt_rel1[c] - m * s;
  }
  __syncthreads();
  float m[10];
#pragma unroll
  for (int k = 0; k < 10; k++) m[k] = 0.f;
  for (int ei = 0; ei < ne; ei++){
    int e = c_INE[c_INOFF[i] + ei];
    float z[20];
#pragma unroll
    for (int c = 0; c < 20; c++){
      float t = y[(((size_t)e * 4 + n) * 20 + c) * L + l];
      z[c] = fmaxf(t * sc[ei][c] + sb[ei][c], 0.f);
    }
#pragma unroll
    for (int k = 0; k < 10; k++){
      float a = b_rel2[k];
#pragma unroll
      for (int c = 0; c < 20; c++) a = fmaf(w2[k * 20 + c], z[c], a);
      m[k] += sigmf(a);
    }
  }
  float h[10];
#pragma unroll
  for (int k = 0; k < 10; k++) h[k] = p_nodes[(((size_t)(i + 1) * 4 + n) * 10 + k) * L + l];
  float g0 = bgs[0], g1 = bgs[1];
#pragma unroll
  for (int k = 0; k < 10; k++){
    g0 = fmaf(wg[k], m[k], g0); g0 = fmaf(wg[10 + k], h[k], g0);
    g1 = fmaf(wg[20 + k], m[k], g1); g1 = fmaf(wg[30 + k], h[k], g1);
  }
  float r = sigmf(g0), zz = sigmf(g1);
  zbuf[((size_t)i * 4 + n) * L + l] = zz;
  float cv[10];
#pragma unroll
  for (int k = 0; k < 10; k++){
    float a = 0.f;
#pragma unroll
    for (int c = 0; c < 10; c++){
      a = fmaf(wc[k * 20 + c], m[c], a);
      a = fmaf(wc[k * 20 + 10 + c], r * h[c], a);
    }
    cv[k] = a;
    cnm[(((size_t)i * 4 + n) * 10 + k) * L + l] = a;
  }
  int wv = tid >> 6, w = tid & 63;
#pragma unroll
  for (int k = 0; k < 10; k++){
    float s1 = cv[k], s2 = cv[k] * cv[k];
    for (int off = 32; off; off >>= 1){ s1 += __shfl_xor(s1, off, 64); s2 += __shfl_xor(s2, off, 64); }
    if (w == 0){ red[wv][2 * k] = s1; red[wv][2 * k + 1] = s2; }
  }
  __syncthreads();
  if (tid < 20){
    float s = red[0][tid] + red[1][tid] + red[2][tid] + red[3][tid];
    int k = tid >> 1, which = tid & 1;
    cpart[(((size_t)(i * 10 + k) * 64) + n * 16 + blockIdx.x) * 2 + which] = s;
  }
}

// ---------------- K13: final node update + part-0 copy; inline cpart reduce ----------------
__global__ __launch_bounds__(256) void k_out(const float* __restrict__ cnm, const float* __restrict__ zbuf,
                                             const float* __restrict__ p_nodes,
                                             const float* __restrict__ cpart,
                                             const float* __restrict__ g_can, const float* __restrict__ bt_can,
                                             float* __restrict__ out){
  int tid = threadIdx.x;
  int idx = blockIdx.x * 256 + tid;
  const int NODE = 4 * 10 * L;
  if (idx < NODE){ out[idx] = p_nodes[idx]; return; }   // whole block is in copy region (NODE % 256 == 0)
  int j = idx - NODE;
  int l = j & (L - 1); int r = j >> 12;
  int k = r % 10; r /= 10; int n = r & 3; int i = r >> 2;
  int ik = i * 10 + k;                                   // uniform across block
  __shared__ float smu, sistd;
  if (tid < 64){
    float s1 = cpart[((size_t)ik * 64 + tid) * 2];
    float s2 = cpart[((size_t)ik * 64 + tid) * 2 + 1];
    for (int off = 32; off; off >>= 1){ s1 += __shfl_xor(s1, off, 64); s2 += __shfl_xor(s2, off, 64); }
    if (tid == 0){
      float m = s1 / 16384.f, v = s2 / 16384.f - m * m;
      smu = m; sistd = rsqrtf(v + 1e-5f);
    }
  }
  __syncthreads();
  float c = cnm[j];
  float cn = (c - smu) * sistd * g_can[ik] + bt_can[ik];
  cn = cn > 0.f ? cn : 0.01f * cn;
  float z = zbuf[((size_t)i * 4 + n) * L + l];
  float h = p_nodes[idx];
  out[idx] = (1.f - z) * h + z * cn;
}

extern "C" void kernel_launch(void* const* d_in, const int* in_sizes, int n_in,
                              void* d_out, int out_size, void* d_ws, size_t ws_size,
                              hipStream_t stream){
  (void)in_sizes; (void)n_in; (void)out_size; (void)ws_size;
  const float* xp      = (const float*)d_in[0];
  const float* p_nodes = (const float*)d_in[1];
  const float* p_atts  = (const float*)d_in[2];
  const float* W_key   = (const float*)d_in[3];
  const float* b_key   = (const float*)d_in[4];
  const float* W_q     = (const float*)d_in[5];
  const float* b_q     = (const float*)d_in[6];
  const float* W_att   = (const float*)d_in[7];
  const float* b_att   = (const float*)d_in[8];
  const float* W_proj  = (const float*)d_in[9];
  const float* g_proj  = (const float*)d_in[10];
  const float* bt_proj = (const float*)d_in[11];
  const float* W_rel1  = (const float*)d_in[12];
  const float* g_rel1  = (const float*)d_in[13];
  const float* bt_rel1 = (const float*)d_in[14];
  const float* W_rel2  = (const float*)d_in[15];
  const float* b_rel2  = (const float*)d_in[16];
  const float* Wg      = (const float*)d_in[17];
  const float* bg      = (const float*)d_in[18];
  const float* Wc      = (const float*)d_in[19];
  const float* g_can   = (const float*)d_in[20];
  const float* bt_can  = (const float*)d_in[21];

  float* out      = (float*)d_out;
  float* fdep_out = out + (size_t)7 * 4 * 10 * L;   // xp_new first, then fdep_att

  float* w = (float*)d_ws;
  size_t off = 0;
  auto alloc = [&](size_t nf){ float* p = w + off; off += nf; return p; };
  float* norm    = alloc((size_t)6 * 4 * L);
  float* cen     = alloc(6 * 4 * 264);
  float* qk      = alloc(6 * 4 * 264);
  float* qb      = alloc(24);
  float* wt2     = alloc(3600);
  float* proj_x  = alloc((size_t)4 * 10 * L);
  float* s_edge  = alloc((size_t)12 * 4 * L);
  float* mpart   = alloc(120 * 256 * 2);
  float* ybuf    = alloc((size_t)12 * 4 * 20 * L);
  float* ypart   = alloc(240 * 32 * 2);
  float* cpart   = alloc(60 * 64 * 2);
  float* cnm     = alloc((size_t)6 * 4 * 10 * L);
  float* zbuf    = alloc((size_t)6 * 4 * L);

  k_softmax_norm<<<25, 256, 0, stream>>>(p_atts, norm, W_rel1, wt2);
  { dim3 g(132, 4); k_centroid<<<g, 256, 0, stream>>>(xp, norm, cen); }
  k_qk<<<24, 256, 0, stream>>>(cen, W_q, b_q, W_key, b_key, qk, qb);
  { dim3 g(64, 4); k_pixel<<<g, 256, 0, stream>>>(xp, p_atts, W_att, b_att, W_proj, qk, qb, fdep_out, s_edge, proj_x, mpart); }
  { dim3 g(8, 4, 24); k_conv3<<<g, 256, 0, stream>>>(proj_x, s_edge, mpart, g_proj, bt_proj, p_nodes, wt2, ybuf, ypart); }
  { dim3 g(16, 4, 6); k_mout_gru<<<g, 256, 0, stream>>>(ybuf, ypart, g_rel1, bt_rel1, W_rel2, b_rel2,
                                                        p_nodes, Wg, bg, Wc, cnm, zbuf, cpart); }
  k_out<<<(7 * 4 * 10 * L) / 256, 256, 0, stream>>>(cnm, zbuf, p_nodes, cpart, g_can, bt_can, out);
}